// Round 3
// baseline (388.836 us; speedup 1.0000x reference)
//
#include <hip/hip_runtime.h>

typedef unsigned int u32;

#define NUM_CAMS 6
#define B_DIM    2
#define C_DIM    64
#define H_DIM    232
#define W_DIM    400
#define HW_DIM   (H_DIM * W_DIM)              // 92800
#define TILE_PX  64
#define TILES_PER_PLANE (HW_DIM / TILE_PX)    // 1450 (exact)
#define PLANES   (NUM_CAMS * B_DIM)           // 12
#define NB       (PLANES * TILES_PER_PLANE)   // 17400 buckets
#define BUCKETS_PER_CAM (B_DIM * TILES_PER_PLANE) // 2900

// ---------------------------------------------------------------------------
// init: out <- vox (float4 copy), zero histogram.
// ---------------------------------------------------------------------------
__global__ __launch_bounds__(256) void init_kernel(
    const float4* __restrict__ vox4, float4* __restrict__ out4,
    u32* __restrict__ hist, int n4, int nbz)
{
    const int t = blockIdx.x * 256 + threadIdx.x;
    if (t < nbz) hist[t] = 0;
    if (t < n4) out4[t] = vox4[t];
}

// ---------------------------------------------------------------------------
// histogram over buckets: key = plane*TILES_PER_PLANE + (pixel>>6)
// grid = (ceil(N/256), NUM_CAMS)
// ---------------------------------------------------------------------------
__global__ __launch_bounds__(256) void hist_kernel(
    const int* __restrict__ bidx, const int* __restrict__ gy,
    const int* __restrict__ gx, const int* __restrict__ mask,
    u32* __restrict__ hist, int N)
{
    const int n = blockIdx.x * 256 + threadIdx.x;
    const int k = blockIdx.y;
    if (n >= N) return;
    if (mask[(size_t)k * N + n] > 0) {
        const int plane = k * B_DIM + bidx[n];
        const int pix = gy[(size_t)k * N + n] * W_DIM + gx[(size_t)k * N + n];
        atomicAdd(&hist[plane * TILES_PER_PLANE + (pix >> 6)], 1u);
    }
}

// ---------------------------------------------------------------------------
// single-block exclusive scan over NB buckets -> offs (NB+1) and cursor (NB)
// ---------------------------------------------------------------------------
__global__ __launch_bounds__(1024) void scan_kernel(
    const u32* __restrict__ hist, u32* __restrict__ offs,
    u32* __restrict__ cursor, int nb)
{
    __shared__ u32 smem[1024];
    __shared__ u32 running;
    const int tid = threadIdx.x;
    if (tid == 0) running = 0;
    __syncthreads();
    for (int base = 0; base < nb; base += 1024) {
        const int i = base + tid;
        const u32 v = (i < nb) ? hist[i] : 0u;
        smem[tid] = v;
        __syncthreads();
        for (int off = 1; off < 1024; off <<= 1) {
            const u32 t = (tid >= off) ? smem[tid - off] : 0u;
            __syncthreads();
            smem[tid] += t;
            __syncthreads();
        }
        const u32 excl = smem[tid] - v + running;   // reads `running`
        if (i < nb) { offs[i] = excl; cursor[i] = excl; }
        __syncthreads();                             // all reads done
        if (tid == 1023) running += smem[1023];
        __syncthreads();
    }
    if (tid == 0) offs[nb] = running;
}

// ---------------------------------------------------------------------------
// scatter masked items into sorted order: packed pixel (plane<<17|pixel) and n
// ---------------------------------------------------------------------------
__global__ __launch_bounds__(256) void scatter_kernel(
    const int* __restrict__ bidx, const int* __restrict__ gy,
    const int* __restrict__ gx, const int* __restrict__ mask,
    u32* __restrict__ cursor, u32* __restrict__ spp, u32* __restrict__ sn, int N)
{
    const int n = blockIdx.x * 256 + threadIdx.x;
    const int k = blockIdx.y;
    if (n >= N) return;
    if (mask[(size_t)k * N + n] > 0) {
        const int plane = k * B_DIM + bidx[n];
        const int pix = gy[(size_t)k * N + n] * W_DIM + gx[(size_t)k * N + n];
        const u32 pos = atomicAdd(&cursor[plane * TILES_PER_PLANE + (pix >> 6)], 1u);
        spp[pos] = ((u32)plane << 17) | (u32)pix;
        sn[pos]  = (u32)n;
    }
}

// ---------------------------------------------------------------------------
// per-camera gather pass: one block per bucket; lane = channel.
// Within one camera each voxel n appears at most once -> non-atomic RMW safe.
// Image lines (16px x 1ch, 64B) are reused ~8.6x from L1/L2 within a bucket.
// ---------------------------------------------------------------------------
__global__ __launch_bounds__(256) void gather_cam_kernel(
    const float* __restrict__ img, const u32* __restrict__ offs,
    const u32* __restrict__ spp, const u32* __restrict__ sn,
    float* __restrict__ out, int bucket0)
{
    const int b = bucket0 + blockIdx.x;
    const u32 s = offs[b];
    const u32 e = offs[b + 1];
    const int w = threadIdx.x >> 6;
    const int c = threadIdx.x & 63;
    for (u32 i = s + w; i < e; i += 4) {
        const u32 pp = spp[i];          // wave-uniform
        const u32 n  = sn[i];           // wave-uniform
        const u32 plane = pp >> 17;
        const u32 pixel = pp & 0x1FFFFu;
        const float v = img[((size_t)plane * C_DIM + c) * HW_DIM + pixel];
        out[(size_t)n * C_DIM + c] += v;
    }
}

// ---------------------------------------------------------------------------
// fallback (round-1 kernel) if workspace is too small
// ---------------------------------------------------------------------------
__global__ __launch_bounds__(256) void fuse_direct_kernel(
    const float* __restrict__ img, const float* __restrict__ vox,
    const int* __restrict__ bidx, const int* __restrict__ gy,
    const int* __restrict__ gx, const int* __restrict__ mask,
    float* __restrict__ out, int N)
{
    const int wave = (int)((blockIdx.x * (size_t)blockDim.x + threadIdx.x) >> 6);
    const int c    = threadIdx.x & 63;
    if (wave >= N) return;
    const int n = wave;
    int m[NUM_CAMS], y[NUM_CAMS], x[NUM_CAMS];
#pragma unroll
    for (int k = 0; k < NUM_CAMS; ++k) {
        m[k] = mask[(size_t)k * N + n];
        y[k] = gy[(size_t)k * N + n];
        x[k] = gx[(size_t)k * N + n];
    }
    const int b = bidx[n];
    float acc = vox[(size_t)n * C_DIM + c];
    const float* base = img + ((size_t)b * C_DIM + c) * HW_DIM;
    float v[NUM_CAMS];
#pragma unroll
    for (int k = 0; k < NUM_CAMS; ++k) {
        v[k] = 0.0f;
        if (m[k] > 0)
            v[k] = base[(size_t)k * (B_DIM * C_DIM * (size_t)HW_DIM)
                        + (size_t)y[k] * W_DIM + (size_t)x[k]];
    }
    acc += ((v[0] + v[1]) + (v[2] + v[3])) + (v[4] + v[5]);
    out[(size_t)n * C_DIM + c] = acc;
}

extern "C" void kernel_launch(void* const* d_in, const int* in_sizes, int n_in,
                              void* d_out, int out_size, void* d_ws, size_t ws_size,
                              hipStream_t stream) {
    const float* img  = (const float*)d_in[0];
    const float* vox  = (const float*)d_in[1];
    const int*   bidx = (const int*)d_in[2];
    const int*   gy   = (const int*)d_in[3];
    const int*   gx   = (const int*)d_in[4];
    const int*   mask = (const int*)d_in[5];
    float* out = (float*)d_out;

    const int N = in_sizes[2];
    const size_t maxItems = (size_t)NUM_CAMS * N;

    // ws layout (u32 units)
    const size_t uHist = 0;
    const size_t uOffs = uHist + NB + 32;
    const size_t uCurs = uOffs + NB + 32;
    const size_t uPP   = uCurs + NB + 32;
    const size_t uSN   = uPP + maxItems + 32;
    const size_t neededBytes = (uSN + maxItems + 32) * sizeof(u32);

    if (ws_size < neededBytes) {
        const int blocks = (N * 64 + 255) / 256;
        fuse_direct_kernel<<<blocks, 256, 0, stream>>>(img, vox, bidx, gy, gx, mask, out, N);
        return;
    }

    u32* ws     = (u32*)d_ws;
    u32* hist   = ws + uHist;
    u32* offs   = ws + uOffs;
    u32* cursor = ws + uCurs;
    u32* spp    = ws + uPP;
    u32* sn     = ws + uSN;

    // 1. init: out <- vox, hist <- 0
    const int n4 = N * (C_DIM / 4);                 // float4 count
    const int initBlocks = (n4 > NB ? n4 : NB) / 256 + 1;
    init_kernel<<<initBlocks, 256, 0, stream>>>(
        (const float4*)vox, (float4*)out, hist, n4, NB);

    // 2. histogram
    dim3 mgrid((N + 255) / 256, NUM_CAMS);
    hist_kernel<<<mgrid, 256, 0, stream>>>(bidx, gy, gx, mask, hist, N);

    // 3. scan
    scan_kernel<<<1, 1024, 0, stream>>>(hist, offs, cursor, NB);

    // 4. scatter into sorted order
    scatter_kernel<<<mgrid, 256, 0, stream>>>(bidx, gy, gx, mask, cursor, spp, sn, N);

    // 5-10. per-camera gather+accumulate (sequential: RMW on out is race-free
    // within a camera, and ordering between cameras is by dispatch order)
    for (int k = 0; k < NUM_CAMS; ++k) {
        gather_cam_kernel<<<BUCKETS_PER_CAM, 256, 0, stream>>>(
            img, offs, spp, sn, out, k * BUCKETS_PER_CAM);
    }
}

// Round 4
// 119.485 us; speedup vs baseline: 3.2543x; 3.2543x over previous
//
#include <hip/hip_runtime.h>
#include <hip/hip_fp16.h>

#define NUM_CAMS 6
#define B_DIM    2
#define C_DIM    64
#define H_DIM    232
#define W_DIM    400
#define HW_DIM   (H_DIM * W_DIM)          // 92800
#define TILES_PER_PLANE (HW_DIM / 64)     // 1450 (exact)
#define PLANES   (NUM_CAMS * B_DIM)       // 12

// ---------------------------------------------------------------------------
// Transpose + downconvert: (k,b,c,h,w) fp32 -> (k,b,h,w,c) fp16.
// 64px x 64ch tile per block. Global reads float4-coalesced; global writes
// half2 (128B/wave-instr); LDS conflicts <=2-way (free on CDNA4).
// ---------------------------------------------------------------------------
__global__ __launch_bounds__(256) void transpose_f16_kernel(
    const float* __restrict__ img,   // (12, 64, HW)
    __half*      __restrict__ wsp)   // (12, HW, 64)
{
    __shared__ float tile[64][65];   // [channel][pixel], +1 pad

    const int t   = blockIdx.x;
    const int kb  = blockIdx.y;
    const int px0 = t * 64;
    const size_t plane_in  = (size_t)kb * C_DIM * HW_DIM;
    const size_t plane_out = (size_t)kb * HW_DIM * C_DIM;
    const int tid = threadIdx.x;

    {
        const int pq = tid & 15;     // which float4 along the 64 pixels
        const int cg = tid >> 4;     // 0..15
#pragma unroll
        for (int r = 0; r < 4; ++r) {
            const int c = r * 16 + cg;
            const float4 v = *(const float4*)&img[plane_in + (size_t)c * HW_DIM + px0 + pq * 4];
            tile[c][pq * 4 + 0] = v.x;
            tile[c][pq * 4 + 1] = v.y;
            tile[c][pq * 4 + 2] = v.z;
            tile[c][pq * 4 + 3] = v.w;
        }
    }
    __syncthreads();
    {
        const int c2 = (tid & 31) * 2;  // channel pair
        const int pg = tid >> 5;        // 0..7
#pragma unroll
        for (int r = 0; r < 8; ++r) {
            const int p = r * 8 + pg;
            const __half2 h = __floats2half2_rn(tile[c2][p], tile[c2 + 1][p]);
            *(__half2*)&wsp[plane_out + (size_t)(px0 + p) * C_DIM + c2] = h;
        }
    }
}

// ---------------------------------------------------------------------------
// Fuse: 16 lanes per voxel, each lane owns 4 channels. Gather per camera is
// one contiguous 128B (fp16) read; vox/out are float4 coalesced.
// ---------------------------------------------------------------------------
__global__ __launch_bounds__(256) void fuse_f16_kernel(
    const __half* __restrict__ wsp,  // (12, HW, 64) channel-last fp16
    const float*  __restrict__ vox,  // (N, 64)
    const int*    __restrict__ bidx, // (N,)
    const int*    __restrict__ gy,   // (6, N)
    const int*    __restrict__ gx,   // (6, N)
    const int*    __restrict__ mask, // (6, N)
    float*        __restrict__ out,  // (N, 64)
    int N)
{
    const size_t gt = blockIdx.x * (size_t)blockDim.x + threadIdx.x;
    const int n = (int)(gt >> 4);
    const int q = (int)(gt & 15);
    if (n >= N) return;

    int m[NUM_CAMS], y[NUM_CAMS], x[NUM_CAMS];
#pragma unroll
    for (int k = 0; k < NUM_CAMS; ++k) {
        m[k] = mask[(size_t)k * N + n];
        y[k] = gy[(size_t)k * N + n];
        x[k] = gx[(size_t)k * N + n];
    }
    const int b = bidx[n];

    float4 acc = ((const float4*)vox)[(size_t)n * 16 + q];

    const __half* base = wsp + (size_t)b * HW_DIM * C_DIM;

    uint2 rv[NUM_CAMS];
#pragma unroll
    for (int k = 0; k < NUM_CAMS; ++k) {
        rv[k] = make_uint2(0u, 0u);           // fp16 zeros
        if (m[k] > 0) {
            const __half* p = base
                + (size_t)k * ((size_t)B_DIM * HW_DIM * C_DIM)
                + ((size_t)y[k] * W_DIM + x[k]) * C_DIM;
            rv[k] = *(const uint2*)(p + q * 4);
        }
    }

#pragma unroll
    for (int k = 0; k < NUM_CAMS; ++k) {
        const __half2 a = *(const __half2*)&rv[k].x;
        const __half2 c = *(const __half2*)&rv[k].y;
        const float2 fa = __half22float2(a);
        const float2 fc = __half22float2(c);
        acc.x += fa.x; acc.y += fa.y; acc.z += fc.x; acc.w += fc.y;
    }

    ((float4*)out)[(size_t)n * 16 + q] = acc;
}

// ---------------------------------------------------------------------------
// Fallback (round-1 kernel) if the workspace is too small for the fp16 copy.
// ---------------------------------------------------------------------------
__global__ __launch_bounds__(256) void fuse_direct_kernel(
    const float* __restrict__ img, const float* __restrict__ vox,
    const int* __restrict__ bidx, const int* __restrict__ gy,
    const int* __restrict__ gx, const int* __restrict__ mask,
    float* __restrict__ out, int N)
{
    const int wave = (int)((blockIdx.x * (size_t)blockDim.x + threadIdx.x) >> 6);
    const int c    = threadIdx.x & 63;
    if (wave >= N) return;
    const int n = wave;
    int m[NUM_CAMS], y[NUM_CAMS], x[NUM_CAMS];
#pragma unroll
    for (int k = 0; k < NUM_CAMS; ++k) {
        m[k] = mask[(size_t)k * N + n];
        y[k] = gy[(size_t)k * N + n];
        x[k] = gx[(size_t)k * N + n];
    }
    const int b = bidx[n];
    float acc = vox[(size_t)n * C_DIM + c];
    const float* base = img + ((size_t)b * C_DIM + c) * HW_DIM;
    float v[NUM_CAMS];
#pragma unroll
    for (int k = 0; k < NUM_CAMS; ++k) {
        v[k] = 0.0f;
        if (m[k] > 0)
            v[k] = base[(size_t)k * (B_DIM * C_DIM * (size_t)HW_DIM)
                        + (size_t)y[k] * W_DIM + (size_t)x[k]];
    }
    acc += ((v[0] + v[1]) + (v[2] + v[3])) + (v[4] + v[5]);
    out[(size_t)n * C_DIM + c] = acc;
}

extern "C" void kernel_launch(void* const* d_in, const int* in_sizes, int n_in,
                              void* d_out, int out_size, void* d_ws, size_t ws_size,
                              hipStream_t stream) {
    const float* img  = (const float*)d_in[0];
    const float* vox  = (const float*)d_in[1];
    const int*   bidx = (const int*)d_in[2];
    const int*   gy   = (const int*)d_in[3];
    const int*   gx   = (const int*)d_in[4];
    const int*   mask = (const int*)d_in[5];
    float* out = (float*)d_out;

    const int N = in_sizes[2];

    const size_t img_half_bytes = (size_t)PLANES * HW_DIM * C_DIM * sizeof(__half); // ~142 MB

    if (ws_size >= img_half_bytes) {
        __half* wsp = (__half*)d_ws;
        dim3 tgrid(TILES_PER_PLANE, PLANES);
        transpose_f16_kernel<<<tgrid, 256, 0, stream>>>(img, wsp);

        const size_t total_threads = (size_t)N * 16;
        const int blocks = (int)((total_threads + 255) / 256);
        fuse_f16_kernel<<<blocks, 256, 0, stream>>>(wsp, vox, bidx, gy, gx, mask, out, N);
    } else {
        const int blocks = (N * 64 + 255) / 256;
        fuse_direct_kernel<<<blocks, 256, 0, stream>>>(img, vox, bidx, gy, gx, mask, out, N);
    }
}

// Round 5
// 106.763 us; speedup vs baseline: 3.6421x; 1.1192x over previous
//
#include <hip/hip_runtime.h>
#include <hip/hip_fp16.h>

#define NUM_CAMS 6
#define B_DIM    2
#define C_DIM    64
#define H_DIM    232
#define W_DIM    400
#define HW_DIM   (H_DIM * W_DIM)          // 92800
#define TILES_PER_PLANE (HW_DIM / 64)     // 1450 (exact)
#define PLANES   (NUM_CAMS * B_DIM)       // 12

typedef float  f4  __attribute__((ext_vector_type(4)));
typedef unsigned int u32;

// ---------------------------------------------------------------------------
// Transpose + downconvert: (k,b,c,h,w) fp32 -> (k,b,h,w,c) fp16.
// img is read ONCE -> non-temporal loads, so the fp16 copy (written here,
// read by the fuse) keeps Infinity-Cache residency.
// ---------------------------------------------------------------------------
__global__ __launch_bounds__(256) void transpose_f16_kernel(
    const float* __restrict__ img,   // (12, 64, HW)
    __half*      __restrict__ wsp)   // (12, HW, 64)
{
    __shared__ float tile[64][65];   // [channel][pixel], +1 pad

    const int t   = blockIdx.x;
    const int kb  = blockIdx.y;
    const int px0 = t * 64;
    const size_t plane_in  = (size_t)kb * C_DIM * HW_DIM;
    const size_t plane_out = (size_t)kb * HW_DIM * C_DIM;
    const int tid = threadIdx.x;

    {
        const int pq = tid & 15;     // which float4 along the 64 pixels
        const int cg = tid >> 4;     // 0..15
#pragma unroll
        for (int r = 0; r < 4; ++r) {
            const int c = r * 16 + cg;
            const f4 v = __builtin_nontemporal_load(
                (const f4*)&img[plane_in + (size_t)c * HW_DIM + px0 + pq * 4]);
            tile[c][pq * 4 + 0] = v.x;
            tile[c][pq * 4 + 1] = v.y;
            tile[c][pq * 4 + 2] = v.z;
            tile[c][pq * 4 + 3] = v.w;
        }
    }
    __syncthreads();
    {
        const int c2 = (tid & 31) * 2;  // channel pair
        const int pg = tid >> 5;        // 0..7
#pragma unroll
        for (int r = 0; r < 8; ++r) {
            const int p = r * 8 + pg;
            const __half2 h = __floats2half2_rn(tile[c2][p], tile[c2 + 1][p]);
            *(__half2*)&wsp[plane_out + (size_t)(px0 + p) * C_DIM + c2] = h;
        }
    }
}

// ---------------------------------------------------------------------------
// Fuse: 16 lanes per voxel, each lane owns 4 channels. Gather per camera is
// one contiguous 128B (fp16) read from the (hopefully L3-resident) copy.
// vox read and out write are stream-once -> non-temporal.
// ---------------------------------------------------------------------------
__global__ __launch_bounds__(256) void fuse_f16_kernel(
    const __half* __restrict__ wsp,  // (12, HW, 64) channel-last fp16
    const float*  __restrict__ vox,  // (N, 64)
    const int*    __restrict__ bidx, // (N,)
    const int*    __restrict__ gy,   // (6, N)
    const int*    __restrict__ gx,   // (6, N)
    const int*    __restrict__ mask, // (6, N)
    float*        __restrict__ out,  // (N, 64)
    int N)
{
    const size_t gt = blockIdx.x * (size_t)blockDim.x + threadIdx.x;
    const int n = (int)(gt >> 4);
    const int q = (int)(gt & 15);
    if (n >= N) return;

    int m[NUM_CAMS], y[NUM_CAMS], x[NUM_CAMS];
#pragma unroll
    for (int k = 0; k < NUM_CAMS; ++k) {
        m[k] = mask[(size_t)k * N + n];
        y[k] = gy[(size_t)k * N + n];
        x[k] = gx[(size_t)k * N + n];
    }
    const int b = bidx[n];

    f4 acc = __builtin_nontemporal_load((const f4*)vox + (size_t)n * 16 + q);

    const __half* base = wsp + (size_t)b * HW_DIM * C_DIM;

    uint2 rv[NUM_CAMS];
#pragma unroll
    for (int k = 0; k < NUM_CAMS; ++k) {
        rv[k] = make_uint2(0u, 0u);           // fp16 zeros
        if (m[k] > 0) {
            const __half* p = base
                + (size_t)k * ((size_t)B_DIM * HW_DIM * C_DIM)
                + ((size_t)y[k] * W_DIM + x[k]) * C_DIM;
            rv[k] = *(const uint2*)(p + q * 4);
        }
    }

#pragma unroll
    for (int k = 0; k < NUM_CAMS; ++k) {
        const __half2 a = *(const __half2*)&rv[k].x;
        const __half2 c = *(const __half2*)&rv[k].y;
        const float2 fa = __half22float2(a);
        const float2 fc = __half22float2(c);
        acc.x += fa.x; acc.y += fa.y; acc.z += fc.x; acc.w += fc.y;
    }

    __builtin_nontemporal_store(acc, (f4*)out + (size_t)n * 16 + q);
}

// ---------------------------------------------------------------------------
// Fallback (round-1 kernel) if the workspace is too small for the fp16 copy.
// ---------------------------------------------------------------------------
__global__ __launch_bounds__(256) void fuse_direct_kernel(
    const float* __restrict__ img, const float* __restrict__ vox,
    const int* __restrict__ bidx, const int* __restrict__ gy,
    const int* __restrict__ gx, const int* __restrict__ mask,
    float* __restrict__ out, int N)
{
    const int wave = (int)((blockIdx.x * (size_t)blockDim.x + threadIdx.x) >> 6);
    const int c    = threadIdx.x & 63;
    if (wave >= N) return;
    const int n = wave;
    int m[NUM_CAMS], y[NUM_CAMS], x[NUM_CAMS];
#pragma unroll
    for (int k = 0; k < NUM_CAMS; ++k) {
        m[k] = mask[(size_t)k * N + n];
        y[k] = gy[(size_t)k * N + n];
        x[k] = gx[(size_t)k * N + n];
    }
    const int b = bidx[n];
    float acc = vox[(size_t)n * C_DIM + c];
    const float* base = img + ((size_t)b * C_DIM + c) * HW_DIM;
    float v[NUM_CAMS];
#pragma unroll
    for (int k = 0; k < NUM_CAMS; ++k) {
        v[k] = 0.0f;
        if (m[k] > 0)
            v[k] = base[(size_t)k * (B_DIM * C_DIM * (size_t)HW_DIM)
                        + (size_t)y[k] * W_DIM + (size_t)x[k]];
    }
    acc += ((v[0] + v[1]) + (v[2] + v[3])) + (v[4] + v[5]);
    out[(size_t)n * C_DIM + c] = acc;
}

extern "C" void kernel_launch(void* const* d_in, const int* in_sizes, int n_in,
                              void* d_out, int out_size, void* d_ws, size_t ws_size,
                              hipStream_t stream) {
    const float* img  = (const float*)d_in[0];
    const float* vox  = (const float*)d_in[1];
    const int*   bidx = (const int*)d_in[2];
    const int*   gy   = (const int*)d_in[3];
    const int*   gx   = (const int*)d_in[4];
    const int*   mask = (const int*)d_in[5];
    float* out = (float*)d_out;

    const int N = in_sizes[2];

    const size_t img_half_bytes = (size_t)PLANES * HW_DIM * C_DIM * sizeof(__half); // ~142 MB

    if (ws_size >= img_half_bytes) {
        __half* wsp = (__half*)d_ws;
        dim3 tgrid(TILES_PER_PLANE, PLANES);
        transpose_f16_kernel<<<tgrid, 256, 0, stream>>>(img, wsp);

        const size_t total_threads = (size_t)N * 16;
        const int blocks = (int)((total_threads + 255) / 256);
        fuse_f16_kernel<<<blocks, 256, 0, stream>>>(wsp, vox, bidx, gy, gx, mask, out, N);
    } else {
        const int blocks = (N * 64 + 255) / 256;
        fuse_direct_kernel<<<blocks, 256, 0, stream>>>(img, vox, bidx, gy, gx, mask, out, N);
    }
}